// Round 8
// baseline (35830.179 us; speedup 1.0000x reference)
//
#include <hip/hip_runtime.h>
#include <math.h>

#define Hh    512
#define G3    1536   // 3*H
#define Tlen  512
#define Bsz   64
#define BH    (Bsz*Hh)   // 32768
#define RING  16         // xga ring slots (L1a -> L1b)
#define YRING 32         // y0 ring slots (L0 -> L1a)

__device__ __forceinline__ float sigmoid_f(float x) { return 1.0f / (1.0f + expf(-x)); }

// Coherent (IF$-level) scalar store: write-through, bypass L1/L2 dirty state.
__device__ __forceinline__ void store_coh(float* p, float v) {
  asm volatile("global_store_dword %0, %1, off sc0 sc1" :: "v"(p), "v"(v) : "memory");
}

// ---------------------------------------------------------------------------
// GEMM: C[M,N] = A[M,K] @ W[N,K]^T + bias[N]  (layer-0 input projection only)
// ---------------------------------------------------------------------------
__global__ __launch_bounds__(256) void gemm_xg(const float* __restrict__ A,
                                               const float* __restrict__ W,
                                               const float* __restrict__ bias,
                                               float* __restrict__ C,
                                               int M, int N, int K) {
  __shared__ float As[16][132];
  __shared__ float Bs[16][132];
  const int nbm = M >> 7;
  const int bm = blockIdx.x % nbm;
  const int bn = blockIdx.x / nbm;
  const int m0 = bm << 7, n0 = bn << 7;
  const int tid = threadIdx.x;
  const int tx = tid & 15, ty = tid >> 4;

  const int row0 = tid >> 2;
  const int kq0  = (tid & 3) << 2;

  const float* Ap0 = &A[(size_t)(m0 + row0) * K + kq0];
  const float* Ap1 = &A[(size_t)(m0 + row0 + 64) * K + kq0];
  const float* Wp0 = &W[(size_t)(n0 + row0) * K + kq0];
  const float* Wp1 = &W[(size_t)(n0 + row0 + 64) * K + kq0];

  float4 ra0 = *(const float4*)(Ap0);
  float4 ra1 = *(const float4*)(Ap1);
  float4 rb0 = *(const float4*)(Wp0);
  float4 rb1 = *(const float4*)(Wp1);

  float acc[8][8];
#pragma unroll
  for (int r = 0; r < 8; r++)
#pragma unroll
    for (int c = 0; c < 8; c++) acc[r][c] = 0.0f;

  for (int kk = 0; kk < K; kk += 16) {
    As[kq0+0][row0]    = ra0.x; As[kq0+1][row0]    = ra0.y; As[kq0+2][row0]    = ra0.z; As[kq0+3][row0]    = ra0.w;
    As[kq0+0][row0+64] = ra1.x; As[kq0+1][row0+64] = ra1.y; As[kq0+2][row0+64] = ra1.z; As[kq0+3][row0+64] = ra1.w;
    Bs[kq0+0][row0]    = rb0.x; Bs[kq0+1][row0]    = rb0.y; Bs[kq0+2][row0]    = rb0.z; Bs[kq0+3][row0]    = rb0.w;
    Bs[kq0+0][row0+64] = rb1.x; Bs[kq0+1][row0+64] = rb1.y; Bs[kq0+2][row0+64] = rb1.z; Bs[kq0+3][row0+64] = rb1.w;
    __syncthreads();
    const int kn = kk + 16;
    if (kn < K) {
      ra0 = *(const float4*)(Ap0 + kn);
      ra1 = *(const float4*)(Ap1 + kn);
      rb0 = *(const float4*)(Wp0 + kn);
      rb1 = *(const float4*)(Wp1 + kn);
    }
#pragma unroll
    for (int k = 0; k < 16; k++) {
      float4 a0 = *(const float4*)&As[k][ty << 3];
      float4 a1 = *(const float4*)&As[k][(ty << 3) + 4];
      float4 b0 = *(const float4*)&Bs[k][tx << 3];
      float4 b1 = *(const float4*)&Bs[k][(tx << 3) + 4];
      float ar[8] = {a0.x, a0.y, a0.z, a0.w, a1.x, a1.y, a1.z, a1.w};
      float br[8] = {b0.x, b0.y, b0.z, b0.w, b1.x, b1.y, b1.z, b1.w};
#pragma unroll
      for (int r = 0; r < 8; r++)
#pragma unroll
        for (int c = 0; c < 8; c++) acc[r][c] = fmaf(ar[r], br[c], acc[r][c]);
    }
    __syncthreads();
  }
  float bl[8];
#pragma unroll
  for (int c = 0; c < 8; c++) bl[c] = bias[n0 + (tx << 3) + c];
#pragma unroll
  for (int r = 0; r < 8; r++) {
    int m = m0 + (ty << 3) + r;
    float4 o0 = make_float4(acc[r][0] + bl[0], acc[r][1] + bl[1], acc[r][2] + bl[2], acc[r][3] + bl[3]);
    float4 o1 = make_float4(acc[r][4] + bl[4], acc[r][5] + bl[5], acc[r][6] + bl[6], acc[r][7] + bl[7]);
    *(float4*)&C[(size_t)m * N + n0 + (tx << 3)]     = o0;
    *(float4*)&C[(size_t)m * N + n0 + (tx << 3) + 4] = o1;
  }
}

// ---------------------------------------------------------------------------
// Fused 2-layer pipelined GRU scan. 768 blocks (3 roles x 8 groups x 32).
// Occupancy pinned via amdgpu_waves_per_eu(3): register budget 512/3 = 170
// (>= ~164 natural demand, measured round 4) and min 3 waves/EU -> 3
// blocks/CU -> all 768 blocks co-resident. NOT __launch_bounds__(256,3):
// round-5 evidence shows that path computes a 512/(2*arg*?) budget (measured
// 128 at arg=2) and would force catastrophic spills at arg=3.
//   role 0 (L0) : layer-0 scan; y0 -> 32-slot ring; backpressure vs L1a.
//   role 1 (L1a): xga(t) = y0(t)@Wih1^T + bih1 -> 16-slot ring;
//                 waits l0(t); backpressure waits l1b >= t-15.
//   role 2 (L1b): hidden matvec + gates; waits l1a(t) and own l1b(t-1).
// Handshake = proven round-4 pattern: sc0sc1 data stores/loads, RELAXED
// stamps, __syncthreads drain before stamping. Lags 31 > 16 > 0 => acyclic.
// ws footprint 202.6 MB < proven 256.5 MiB envelope (round-6 crash suspect).
// ---------------------------------------------------------------------------
__global__ __attribute__((amdgpu_waves_per_eu(3))) __launch_bounds__(256) void gru_pipe(
    const float* __restrict__ xg0,   // [T,B,3H] layer-0 input proj
    const float* __restrict__ Whh0,  // [3H,H]
    const float* __restrict__ bhh0,  // [3H]
    const float* __restrict__ Wih1,  // [3H,H]
    const float* __restrict__ bih1,  // [3H]
    const float* __restrict__ Whh1,  // [3H,H]
    const float* __restrict__ bhh1,  // [3H]
    float* __restrict__ y1,          // [T,B,H] output
    float* __restrict__ hn0,         // [B,H]
    float* __restrict__ hn1,         // [B,H]
    float* h0buf, float* h1buf,      // 2 slots of [B][H] each
    float* y0ring,                   // [YRING][B][H] coherent ring
    float* ring,                     // [RING][B][3H] xga ring
    int* l0slots, int* l1aslots, int* l1bslots) {
  const int tid = threadIdx.x;
  const int jl = tid >> 4;           // 0..15
  const int ks = tid & 15;           // 0..15
  const int bgrp = blockIdx.x & 7;
  const int rr   = blockIdx.x >> 3;  // 0..95
  const int role = rr >> 5;          // 0=L0, 1=L1a, 2=L1b
  const int jgrp = rr & 31;          // 0..31
  const int j0 = jgrp << 4;
  const int b0 = bgrp << 3;
  const int k0 = ks << 5;

  __shared__ float4 hs4[1024];       // one 8x128-float4 tile (swizzled)

  int* myl0  = l0slots  + (bgrp * 32 + jgrp) * 32;
  int* gl0   = l0slots  + bgrp * 32 * 32;
  int* myl1a = l1aslots + (bgrp * 32 + jgrp) * 32;
  int* gl1a  = l1aslots + bgrp * 32 * 32;
  int* myl1b = l1bslots + (bgrp * 32 + jgrp) * 32;
  int* gl1b  = l1bslots + bgrp * 32 * 32;

  int off[8];
#pragma unroll
  for (int q = 0; q < 8; q++) off[q] = (ks * 8 + q) ^ (ks & 7);
  const int fq = tid & 127;
  const int brow = tid >> 7;
  const int fswz = fq ^ ((fq >> 3) & 7);

  if (role == 0) {
    // ================= L0: layer-0 scan =================
    float4 wv[3][8];
#pragma unroll
    for (int g = 0; g < 3; g++) {
      const float* wp = &Whh0[(size_t)(g * Hh + j0 + jl) * Hh + k0];
#pragma unroll
      for (int q = 0; q < 8; q++) wv[g][q] = *(const float4*)&wp[q * 4];
    }
    float bh[3];
#pragma unroll
    for (int g = 0; g < 3; g++) bh[g] = bhh0[g * Hh + j0 + jl];

    float xr = 0.0f, xz = 0.0f, xn = 0.0f;
    if (ks < 8) {
      const float* xp = &xg0[(size_t)(b0 + ks) * G3 + j0 + jl];
      xr = xp[0]; xz = xp[Hh]; xn = xp[2 * Hh];
    }

    int cur = 0;
    for (int t = 0; t < Tlen; t++) {
      const float4* hsrc = (const float4*)(h0buf + cur * BH) + (size_t)(b0 + brow) * 128 + fq;
      float4 h0, h1, h2, h3;
      {
        const float4* p0 = hsrc;
        const float4* p1 = hsrc + 2 * 128;
        const float4* p2 = hsrc + 4 * 128;
        const float4* p3 = hsrc + 6 * 128;
        asm volatile(
            "global_load_dwordx4 %0, %4, off sc0 sc1\n\t"
            "global_load_dwordx4 %1, %5, off sc0 sc1\n\t"
            "global_load_dwordx4 %2, %6, off sc0 sc1\n\t"
            "global_load_dwordx4 %3, %7, off sc0 sc1\n\t"
            "s_waitcnt vmcnt(0)"
            : "=&v"(h0), "=&v"(h1), "=&v"(h2), "=&v"(h3)
            : "v"(p0), "v"(p1), "v"(p2), "v"(p3)
            : "memory");
      }
      hs4[(brow + 0) * 128 + fswz] = h0;
      hs4[(brow + 2) * 128 + fswz] = h1;
      hs4[(brow + 4) * 128 + fswz] = h2;
      hs4[(brow + 6) * 128 + fswz] = h3;
      __syncthreads();

      float acc[3][8];
#pragma unroll
      for (int b = 0; b < 8; b++) {
        float4 hv[8];
#pragma unroll
        for (int q = 0; q < 8; q++) hv[q] = hs4[b * 128 + off[q]];
#pragma unroll
        for (int g = 0; g < 3; g++) {
          float s = 0.0f;
#pragma unroll
          for (int q = 0; q < 8; q++) {
            s = fmaf(wv[g][q].x, hv[q].x, s);
            s = fmaf(wv[g][q].y, hv[q].y, s);
            s = fmaf(wv[g][q].z, hv[q].z, s);
            s = fmaf(wv[g][q].w, hv[q].w, s);
          }
          acc[g][b] = s;
        }
      }
#pragma unroll
      for (int d = 1; d < 16; d <<= 1) {
#pragma unroll
        for (int g = 0; g < 3; g++)
#pragma unroll
          for (int b = 0; b < 8; b++) acc[g][b] += __shfl_xor(acc[g][b], d);
      }

      if (ks < 8) {
        int b = b0 + ks;
        int e = j0 + jl;
        float r = sigmoid_f(xr + acc[0][ks] + bh[0]);
        float z = sigmoid_f(xz + acc[1][ks] + bh[1]);
        float n = tanhf(xn + r * (acc[2][ks] + bh[2]));
        int f = e >> 2;
        float4 hp4 = hs4[ks * 128 + (f ^ ((f >> 3) & 7))];
        float hp = ((const float*)&hp4)[e & 3];
        float hnew = (1.0f - z) * n + z * hp;
        store_coh(&h0buf[(cur ^ 1) * BH + (size_t)b * Hh + e], hnew);
        store_coh(&y0ring[(size_t)(t & (YRING - 1)) * BH + (size_t)b * Hh + e], hnew);
        if (t == Tlen - 1) hn0[(size_t)b * Hh + e] = hnew;
      }

      __syncthreads();   // drain all waves' coherent stores
      if (tid == 0) {
        __hip_atomic_store(myl0, t + 1, __ATOMIC_RELAXED, __HIP_MEMORY_SCOPE_AGENT);
      }
      if (t == Tlen - 1) break;

      float nxr = 0.0f, nxz = 0.0f, nxn = 0.0f;
      if (ks < 8) {
        const float* xp = &xg0[((size_t)(t + 1) * Bsz + (b0 + ks)) * G3 + j0 + jl];
        nxr = xp[0]; nxz = xp[Hh]; nxn = xp[2 * Hh];
      }
      // spin: lanes 0-31 lockstep on own group's L0 stamps;
      // lanes 32-63 y0-ring backpressure: gl1a >= t-30 before writing slot (t+1)&31
      if (tid < 64) {
        const int target = t + 1;
        for (;;) {
          int v;
          if (tid < 32)
            v = __hip_atomic_load(gl0 + tid * 32, __ATOMIC_RELAXED, __HIP_MEMORY_SCOPE_AGENT);
          else
            v = __hip_atomic_load(gl1a + (tid - 32) * 32, __ATOMIC_RELAXED, __HIP_MEMORY_SCOPE_AGENT) + (YRING - 1);
          if (!__any(v < target)) break;
          __builtin_amdgcn_s_sleep(1);
        }
      }
      __syncthreads();
      xr = nxr; xz = nxz; xn = nxn;
      cur ^= 1;
    }
  } else if (role == 1) {
    // ================= L1a: layer-1 input projection =================
    float4 wi[3][8];
#pragma unroll
    for (int g = 0; g < 3; g++) {
      const float* wp = &Wih1[(size_t)(g * Hh + j0 + jl) * Hh + k0];
#pragma unroll
      for (int q = 0; q < 8; q++) wi[g][q] = *(const float4*)&wp[q * 4];
    }
    float bi[3];
#pragma unroll
    for (int g = 0; g < 3; g++) bi[g] = bih1[g * Hh + j0 + jl];

    for (int t = 0; t < Tlen; t++) {
      // wait: y0(t) ready (gl0 >= t+1); ring1 slot free (gl1b >= t-15)
      if (tid < 64) {
        const int target = t + 1;
        for (;;) {
          int v;
          if (tid < 32)
            v = __hip_atomic_load(gl0 + tid * 32, __ATOMIC_RELAXED, __HIP_MEMORY_SCOPE_AGENT);
          else
            v = __hip_atomic_load(gl1b + (tid - 32) * 32, __ATOMIC_RELAXED, __HIP_MEMORY_SCOPE_AGENT) + RING;
          if (!__any(v < target)) break;
          __builtin_amdgcn_s_sleep(1);
        }
      }
      __syncthreads();

      // stage y0(t) tile from ring (coherent)
      const float4* ysrc = (const float4*)(y0ring + (size_t)(t & (YRING - 1)) * BH) + (size_t)(b0 + brow) * 128 + fq;
      float4 a0, a1, a2, a3;
      {
        const float4* p0 = ysrc;
        const float4* p1 = ysrc + 2 * 128;
        const float4* p2 = ysrc + 4 * 128;
        const float4* p3 = ysrc + 6 * 128;
        asm volatile(
            "global_load_dwordx4 %0, %4, off sc0 sc1\n\t"
            "global_load_dwordx4 %1, %5, off sc0 sc1\n\t"
            "global_load_dwordx4 %2, %6, off sc0 sc1\n\t"
            "global_load_dwordx4 %3, %7, off sc0 sc1\n\t"
            "s_waitcnt vmcnt(0)"
            : "=&v"(a0), "=&v"(a1), "=&v"(a2), "=&v"(a3)
            : "v"(p0), "v"(p1), "v"(p2), "v"(p3)
            : "memory");
      }
      hs4[(brow + 0) * 128 + fswz] = a0;
      hs4[(brow + 2) * 128 + fswz] = a1;
      hs4[(brow + 4) * 128 + fswz] = a2;
      hs4[(brow + 6) * 128 + fswz] = a3;
      __syncthreads();

      float xga[3][8];
#pragma unroll
      for (int b = 0; b < 8; b++) {
        float4 hv[8];
#pragma unroll
        for (int q = 0; q < 8; q++) hv[q] = hs4[b * 128 + off[q]];
#pragma unroll
        for (int g = 0; g < 3; g++) {
          float s = 0.0f;
#pragma unroll
          for (int q = 0; q < 8; q++) {
            s = fmaf(wi[g][q].x, hv[q].x, s);
            s = fmaf(wi[g][q].y, hv[q].y, s);
            s = fmaf(wi[g][q].z, hv[q].z, s);
            s = fmaf(wi[g][q].w, hv[q].w, s);
          }
          xga[g][b] = s;
        }
      }
#pragma unroll
      for (int d = 1; d < 16; d <<= 1) {
#pragma unroll
        for (int g = 0; g < 3; g++)
#pragma unroll
          for (int b = 0; b < 8; b++) xga[g][b] += __shfl_xor(xga[g][b], d);
      }

      if (ks < 8) {
        int b = b0 + ks;
        int e = j0 + jl;
        float* rp = ring + ((size_t)(t & (RING - 1)) * Bsz + b) * G3 + e;
        store_coh(rp,          xga[0][ks] + bi[0]);
        store_coh(rp + Hh,     xga[1][ks] + bi[1]);
        store_coh(rp + 2 * Hh, xga[2][ks] + bi[2]);
      }

      __syncthreads();   // drain
      if (tid == 0) {
        __hip_atomic_store(myl1a, t + 1, __ATOMIC_RELAXED, __HIP_MEMORY_SCOPE_AGENT);
      }
    }
  } else {
    // ================= L1b: layer-1 hidden matvec + gates =================
    float4 wh[3][8];
#pragma unroll
    for (int g = 0; g < 3; g++) {
      const float* wp = &Whh1[(size_t)(g * Hh + j0 + jl) * Hh + k0];
#pragma unroll
      for (int q = 0; q < 8; q++) wh[g][q] = *(const float4*)&wp[q * 4];
    }
    float bh[3];
#pragma unroll
    for (int g = 0; g < 3; g++) bh[g] = bhh1[g * Hh + j0 + jl];

    int cur = 0;
    for (int t = 0; t < Tlen; t++) {
      // wait: xga(t) ready (gl1a >= t+1) AND h1(t-1) ready (gl1b >= t)
      if (tid < 64) {
        const int target = t + 1;
        for (;;) {
          int v;
          if (tid < 32)
            v = __hip_atomic_load(gl1a + tid * 32, __ATOMIC_RELAXED, __HIP_MEMORY_SCOPE_AGENT);
          else
            v = __hip_atomic_load(gl1b + (tid - 32) * 32, __ATOMIC_RELAXED, __HIP_MEMORY_SCOPE_AGENT) + 1;
          if (!__any(v < target)) break;
          __builtin_amdgcn_s_sleep(1);
        }
      }
      __syncthreads();

      // stage h1(t-1) tile (coherent, 4-load asm)
      const float4* hsrc = (const float4*)(h1buf + cur * BH) + (size_t)(b0 + brow) * 128 + fq;
      float4 h0, h1, h2, h3;
      {
        const float4* p0 = hsrc;
        const float4* p1 = hsrc + 2 * 128;
        const float4* p2 = hsrc + 4 * 128;
        const float4* p3 = hsrc + 6 * 128;
        asm volatile(
            "global_load_dwordx4 %0, %4, off sc0 sc1\n\t"
            "global_load_dwordx4 %1, %5, off sc0 sc1\n\t"
            "global_load_dwordx4 %2, %6, off sc0 sc1\n\t"
            "global_load_dwordx4 %3, %7, off sc0 sc1\n\t"
            "s_waitcnt vmcnt(0)"
            : "=&v"(h0), "=&v"(h1), "=&v"(h2), "=&v"(h3)
            : "v"(p0), "v"(p1), "v"(p2), "v"(p3)
            : "memory");
      }
      // xga scalars (separate small asm; lanes ks>=8 load harmless valid addrs)
      const float* rp = ring + ((size_t)(t & (RING - 1)) * Bsz + (b0 + (ks & 7))) * G3 + j0 + jl;
      float xr, xz, xn;
      {
        asm volatile(
            "global_load_dword %0, %3, off sc0 sc1\n\t"
            "global_load_dword %1, %4, off sc0 sc1\n\t"
            "global_load_dword %2, %5, off sc0 sc1\n\t"
            "s_waitcnt vmcnt(0)"
            : "=&v"(xr), "=&v"(xz), "=&v"(xn)
            : "v"(rp), "v"(rp + Hh), "v"(rp + 2 * Hh)
            : "memory");
      }
      hs4[(brow + 0) * 128 + fswz] = h0;
      hs4[(brow + 2) * 128 + fswz] = h1;
      hs4[(brow + 4) * 128 + fswz] = h2;
      hs4[(brow + 6) * 128 + fswz] = h3;
      __syncthreads();

      float acc[3][8];
#pragma unroll
      for (int b = 0; b < 8; b++) {
        float4 hv[8];
#pragma unroll
        for (int q = 0; q < 8; q++) hv[q] = hs4[b * 128 + off[q]];
#pragma unroll
        for (int g = 0; g < 3; g++) {
          float s = 0.0f;
#pragma unroll
          for (int q = 0; q < 8; q++) {
            s = fmaf(wh[g][q].x, hv[q].x, s);
            s = fmaf(wh[g][q].y, hv[q].y, s);
            s = fmaf(wh[g][q].z, hv[q].z, s);
            s = fmaf(wh[g][q].w, hv[q].w, s);
          }
          acc[g][b] = s;
        }
      }
#pragma unroll
      for (int d = 1; d < 16; d <<= 1) {
#pragma unroll
        for (int g = 0; g < 3; g++)
#pragma unroll
          for (int b = 0; b < 8; b++) acc[g][b] += __shfl_xor(acc[g][b], d);
      }

      if (ks < 8) {
        int b = b0 + ks;
        int e = j0 + jl;
        float r = sigmoid_f(xr + acc[0][ks] + bh[0]);
        float z = sigmoid_f(xz + acc[1][ks] + bh[1]);
        float n = tanhf(xn + r * (acc[2][ks] + bh[2]));
        int f = e >> 2;
        float4 hp4 = hs4[ks * 128 + (f ^ ((f >> 3) & 7))];
        float hp = ((const float*)&hp4)[e & 3];
        float hnew = (1.0f - z) * n + z * hp;
        store_coh(&h1buf[(cur ^ 1) * BH + (size_t)b * Hh + e], hnew);
        y1[((size_t)t * Bsz + b) * Hh + e] = hnew;
        if (t == Tlen - 1) hn1[(size_t)b * Hh + e] = hnew;
      }

      if (t == Tlen - 1) break;
      __syncthreads();   // drain
      if (tid == 0) {
        __hip_atomic_store(myl1b, t + 1, __ATOMIC_RELAXED, __HIP_MEMORY_SCOPE_AGENT);
      }
      cur ^= 1;
    }
  }
}

// ---------------------------------------------------------------------------
// Launch
// ---------------------------------------------------------------------------
extern "C" void kernel_launch(void* const* d_in, const int* in_sizes, int n_in,
                              void* d_out, int out_size, void* d_ws, size_t ws_size,
                              hipStream_t stream) {
  const float* x     = (const float*)d_in[0];
  const float* Wih0  = (const float*)d_in[1];
  const float* Whh0  = (const float*)d_in[2];
  const float* bih0  = (const float*)d_in[3];
  const float* bhh0  = (const float*)d_in[4];
  const float* Wih1  = (const float*)d_in[5];
  const float* Whh1  = (const float*)d_in[6];
  const float* bih1  = (const float*)d_in[7];
  const float* bhh1  = (const float*)d_in[8];

  float* out = (float*)d_out;
  float* y1   = out;                       // [T,B,H]
  float* hn0  = out + (size_t)Tlen * BH;   // [B,H]
  float* hn1  = hn0 + BH;                  // [B,H]

  // workspace layout (floats) -- total 53,108,736 floats = 202.6 MB
  //  [0, 24576)     stamps: 3 roles x 8 groups x 32 blocks x 32 ints
  //  h0buf/h1buf    2 slots each of [B][H]
  //  xg0 buffer     T*B*3H floats (192 MB)
  //  y0 ring        YRING*B*H floats (4 MB)
  //  ring1          RING*B*3H floats (6 MB)
  float* ws       = (float*)d_ws;
  int*   l0slots  = (int*)d_ws;
  int*   l1aslots = l0slots + 8192;
  int*   l1bslots = l1aslots + 8192;
  float* h0buf    = ws + 24576;
  float* h1buf    = h0buf + 2 * BH;
  float* xg0buf   = h1buf + 2 * BH;
  float* y0ring   = xg0buf + (size_t)Tlen * Bsz * G3;
  float* ringbuf  = y0ring + (size_t)YRING * BH;

  const int M = Tlen * Bsz;  // 32768

  hipMemsetAsync(l0slots, 0, 3 * 8192 * sizeof(int), stream);
  hipMemsetAsync(h0buf, 0, BH * sizeof(float), stream);   // h0(0) = 0
  hipMemsetAsync(h1buf, 0, BH * sizeof(float), stream);   // h1(0) = 0

  dim3 gemm_grid((M / 128) * (G3 / 128));  // 3072 blocks

  // layer-0 input projection (x @ W_ih0^T + b_ih0)
  gemm_xg<<<gemm_grid, 256, 0, stream>>>(x, Wih0, bih0, xg0buf, M, G3, 256);

  // fused pipelined 2-layer scan
  gru_pipe<<<768, 256, 0, stream>>>(xg0buf, Whh0, bhh0, Wih1, bih1, Whh1, bhh1,
                                    y1, hn0, hn1, h0buf, h1buf, y0ring, ringbuf,
                                    l0slots, l1aslots, l1bslots);
}

// Round 13
// 8064.975 us; speedup vs baseline: 4.4427x; 4.4427x over previous
//
#include <hip/hip_runtime.h>
#include <math.h>

#define Hh   512
#define G3   1536   // 3*H
#define Tlen 512
#define Bsz  64
#define BH   (Bsz*Hh)   // 32768

__device__ __forceinline__ float sigmoid_f(float x) { return 1.0f / (1.0f + expf(-x)); }

// Coherent (IF$-level) scalar store: write-through, bypass L1/L2 dirty state.
__device__ __forceinline__ void store_coh(float* p, float v) {
  asm volatile("global_store_dword %0, %1, off sc0 sc1" :: "v"(p), "v"(v) : "memory");
}

// ---------------------------------------------------------------------------
// GEMM: C[M,N] = A[M,K] @ W[N,K]^T + bias[N]   (fp32, 128x128 tile, 8x8/thread)
// Proven round-4 kernel, unchanged.
// ---------------------------------------------------------------------------
__global__ __launch_bounds__(256) void gemm_xg(const float* __restrict__ A,
                                               const float* __restrict__ W,
                                               const float* __restrict__ bias,
                                               float* __restrict__ C,
                                               int M, int N, int K) {
  __shared__ float As[16][132];
  __shared__ float Bs[16][132];
  const int nbm = M >> 7;
  const int bm = blockIdx.x % nbm;
  const int bn = blockIdx.x / nbm;
  const int m0 = bm << 7, n0 = bn << 7;
  const int tid = threadIdx.x;
  const int tx = tid & 15, ty = tid >> 4;

  const int row0 = tid >> 2;
  const int kq0  = (tid & 3) << 2;

  const float* Ap0 = &A[(size_t)(m0 + row0) * K + kq0];
  const float* Ap1 = &A[(size_t)(m0 + row0 + 64) * K + kq0];
  const float* Wp0 = &W[(size_t)(n0 + row0) * K + kq0];
  const float* Wp1 = &W[(size_t)(n0 + row0 + 64) * K + kq0];

  float4 ra0 = *(const float4*)(Ap0);
  float4 ra1 = *(const float4*)(Ap1);
  float4 rb0 = *(const float4*)(Wp0);
  float4 rb1 = *(const float4*)(Wp1);

  float acc[8][8];
#pragma unroll
  for (int r = 0; r < 8; r++)
#pragma unroll
    for (int c = 0; c < 8; c++) acc[r][c] = 0.0f;

  for (int kk = 0; kk < K; kk += 16) {
    As[kq0+0][row0]    = ra0.x; As[kq0+1][row0]    = ra0.y; As[kq0+2][row0]    = ra0.z; As[kq0+3][row0]    = ra0.w;
    As[kq0+0][row0+64] = ra1.x; As[kq0+1][row0+64] = ra1.y; As[kq0+2][row0+64] = ra1.z; As[kq0+3][row0+64] = ra1.w;
    Bs[kq0+0][row0]    = rb0.x; Bs[kq0+1][row0]    = rb0.y; Bs[kq0+2][row0]    = rb0.z; Bs[kq0+3][row0]    = rb0.w;
    Bs[kq0+0][row0+64] = rb1.x; Bs[kq0+1][row0+64] = rb1.y; Bs[kq0+2][row0+64] = rb1.z; Bs[kq0+3][row0+64] = rb1.w;
    __syncthreads();
    const int kn = kk + 16;
    if (kn < K) {
      ra0 = *(const float4*)(Ap0 + kn);
      ra1 = *(const float4*)(Ap1 + kn);
      rb0 = *(const float4*)(Wp0 + kn);
      rb1 = *(const float4*)(Wp1 + kn);
    }
#pragma unroll
    for (int k = 0; k < 16; k++) {
      float4 a0 = *(const float4*)&As[k][ty << 3];
      float4 a1 = *(const float4*)&As[k][(ty << 3) + 4];
      float4 b0 = *(const float4*)&Bs[k][tx << 3];
      float4 b1 = *(const float4*)&Bs[k][(tx << 3) + 4];
      float ar[8] = {a0.x, a0.y, a0.z, a0.w, a1.x, a1.y, a1.z, a1.w};
      float br[8] = {b0.x, b0.y, b0.z, b0.w, b1.x, b1.y, b1.z, b1.w};
#pragma unroll
      for (int r = 0; r < 8; r++)
#pragma unroll
        for (int c = 0; c < 8; c++) acc[r][c] = fmaf(ar[r], br[c], acc[r][c]);
    }
    __syncthreads();
  }
  float bl[8];
#pragma unroll
  for (int c = 0; c < 8; c++) bl[c] = bias[n0 + (tx << 3) + c];
#pragma unroll
  for (int r = 0; r < 8; r++) {
    int m = m0 + (ty << 3) + r;
    float4 o0 = make_float4(acc[r][0] + bl[0], acc[r][1] + bl[1], acc[r][2] + bl[2], acc[r][3] + bl[3]);
    float4 o1 = make_float4(acc[r][4] + bl[4], acc[r][5] + bl[5], acc[r][6] + bl[6], acc[r][7] + bl[7]);
    *(float4*)&C[(size_t)m * N + n0 + (tx << 3)]     = o0;
    *(float4*)&C[(size_t)m * N + n0 + (tx << 3) + 4] = o1;
  }
}

// ---------------------------------------------------------------------------
// GRU scan (one layer) -- round-4 proven topology + wave-level handshake.
// 256 blocks x 256 threads; 8 independent batch-groups of 32 blocks.
// Handshake (fence-free, proven): sc0sc1 h stores -> per-WAVE vmcnt(0) drain
// -> per-wave RELAXED stamp (128 slots/group, 32B stride) -> all-wave spin.
// Changes vs round 4 (each cuts the per-step critical path):
//   * wave-level stamps: no pre-stamp __syncthreads, stragglers decoupled
//   * y store moved after the stamp (drain = 1 coherent store only)
//   * post-spin __syncthreads removed (safe: spin-exit certifies all hs4
//     reads of step t retired; threads re-stage only their own hs4 slots;
//     post-staging sync still guards compute)
// ---------------------------------------------------------------------------
__global__ __launch_bounds__(256, 1) void gru_scan(
    const float* __restrict__ xg,   // [T, B, 3H]
    const float* __restrict__ Whh,  // [3H, H]
    const float* __restrict__ bhh,  // [3H]
    float* __restrict__ y,          // [T, B, H]
    float* __restrict__ hfin,       // [B, H] final hidden
    float* hbuf,                    // 2 slots of [B][H]
    int* slots,                     // 8 groups x 32 blocks x 4 waves x 8 ints
    int base) {                     // stamp base (0 layer0, Tlen layer1)
  const int tid = threadIdx.x;
  const int jl = tid >> 4;          // 0..15  hidden-j within block
  const int ks = tid & 15;          // 0..15  k-chunk (32 floats each)
  const int bgrp = blockIdx.x & 7;
  const int jgrp = blockIdx.x >> 3; // 0..31
  const int j0 = jgrp << 4;
  const int b0 = bgrp << 3;
  const int k0 = ks << 5;

  int* gslots  = slots + bgrp * 1024;          // 128 wave-slots (stride 8 ints)
  int* blkslot = gslots + jgrp * 32;           // this block's 4 wave slots

  __shared__ float4 hs4[8 * 128];   // 8 batch rows x 128 float4 (swizzled)

  // persistent W_hh fragment: 3 gates x 32 floats
  float4 wv[3][8];
#pragma unroll
  for (int g = 0; g < 3; g++) {
    const float* wp = &Whh[(size_t)(g * Hh + j0 + jl) * Hh + k0];
#pragma unroll
    for (int q = 0; q < 8; q++) wv[g][q] = *(const float4*)&wp[q * 4];
  }
  float bh[3];
#pragma unroll
  for (int g = 0; g < 3; g++) bh[g] = bhh[g * Hh + j0 + jl];

  // swizzled LDS float4 offsets for this thread's k-chunk
  int off[8];
#pragma unroll
  for (int q = 0; q < 8; q++) off[q] = (ks * 8 + q) ^ (ks & 7);

  // staging geometry: 4 rows per thread, same f, rows brow+{0,2,4,6}
  const int fq = tid & 127;
  const int brow = tid >> 7;
  const int fswz = fq ^ ((fq >> 3) & 7);

  // prologue: xg[0]
  float xr = 0.0f, xz = 0.0f, xn = 0.0f;
  if (ks < 8) {
    const float* xp = &xg[(size_t)(b0 + ks) * G3 + j0 + jl];
    xr = xp[0]; xz = xp[Hh]; xn = xp[2 * Hh];
  }

  int cur = 0;

  for (int t = 0; t < Tlen; t++) {
    // ---- stage h_prev rows [b0, b0+8) into LDS via coherent loads ----
    const float4* hsrc = (const float4*)(hbuf + cur * BH) + (size_t)(b0 + brow) * 128 + fq;
    float4 h0, h1, h2, h3;
    {
      const float4* p0 = hsrc;
      const float4* p1 = hsrc + 2 * 128;
      const float4* p2 = hsrc + 4 * 128;
      const float4* p3 = hsrc + 6 * 128;
      asm volatile(
          "global_load_dwordx4 %0, %4, off sc0 sc1\n\t"
          "global_load_dwordx4 %1, %5, off sc0 sc1\n\t"
          "global_load_dwordx4 %2, %6, off sc0 sc1\n\t"
          "global_load_dwordx4 %3, %7, off sc0 sc1\n\t"
          "s_waitcnt vmcnt(0)"
          : "=&v"(h0), "=&v"(h1), "=&v"(h2), "=&v"(h3)
          : "v"(p0), "v"(p1), "v"(p2), "v"(p3)
          : "memory");
    }
    hs4[(brow + 0) * 128 + fswz] = h0;
    hs4[(brow + 2) * 128 + fswz] = h1;
    hs4[(brow + 4) * 128 + fswz] = h2;
    hs4[(brow + 6) * 128 + fswz] = h3;
    __syncthreads();   // the ONE sync per step: staging complete before compute

    // ---- partial dots: 3 gates x 8 batches over this thread's 32 k ----
    float acc[3][8];
#pragma unroll
    for (int b = 0; b < 8; b++) {
      float4 hv[8];
#pragma unroll
      for (int q = 0; q < 8; q++) hv[q] = hs4[b * 128 + off[q]];
#pragma unroll
      for (int g = 0; g < 3; g++) {
        float s = 0.0f;
#pragma unroll
        for (int q = 0; q < 8; q++) {
          s = fmaf(wv[g][q].x, hv[q].x, s);
          s = fmaf(wv[g][q].y, hv[q].y, s);
          s = fmaf(wv[g][q].z, hv[q].z, s);
          s = fmaf(wv[g][q].w, hv[q].w, s);
        }
        acc[g][b] = s;
      }
    }
    // ---- butterfly reduce across the 16 k-chunks (same wave) ----
#pragma unroll
    for (int d = 1; d < 16; d <<= 1) {
#pragma unroll
      for (int g = 0; g < 3; g++)
#pragma unroll
        for (int b = 0; b < 8; b++) acc[g][b] += __shfl_xor(acc[g][b], d);
    }

    // ---- gates: lanes ks<8 handle batch (b0+ks), hidden (j0+jl) ----
    float hnew = 0.0f;
    int b = 0, e = 0;
    if (ks < 8) {
      b = b0 + ks;
      e = j0 + jl;
      float r = sigmoid_f(xr + acc[0][ks] + bh[0]);
      float z = sigmoid_f(xz + acc[1][ks] + bh[1]);
      float n = tanhf(xn + r * (acc[2][ks] + bh[2]));
      int f = e >> 2;
      float4 hp4 = hs4[ks * 128 + (f ^ ((f >> 3) & 7))];
      float hp = ((const float*)&hp4)[e & 3];
      hnew = (1.0f - z) * n + z * hp;
      store_coh(&hbuf[(cur ^ 1) * BH + (size_t)b * Hh + e], hnew);  // ONLY store before drain
    }

    if (t == Tlen - 1) {
      if (ks < 8) {
        y[((size_t)t * Bsz + b) * Hh + e] = hnew;
        hfin[(size_t)b * Hh + e] = hnew;
      }
      break;   // nobody consumes the last barrier
    }

    // ---- wave-level drain + stamp (no block sync on the critical path) ----
    asm volatile("s_waitcnt vmcnt(0)" ::: "memory");
    if ((tid & 63) == 0) {
      __hip_atomic_store(blkslot + (tid >> 6) * 8, base + t + 1,
                         __ATOMIC_RELAXED, __HIP_MEMORY_SCOPE_AGENT);
    }

    // ---- y store + xg[t+1] prefetch AFTER stamp: latency hides under spin ----
    if (ks < 8) y[((size_t)t * Bsz + b) * Hh + e] = hnew;
    float nxr = 0.0f, nxz = 0.0f, nxn = 0.0f;
    if (ks < 8) {
      const float* xp = &xg[((size_t)(t + 1) * Bsz + (b0 + ks)) * G3 + j0 + jl];
      nxr = xp[0]; nxz = xp[Hh]; nxn = xp[2 * Hh];
    }

    // ---- all-wave spin over the group's 128 wave-slots (2 per lane) ----
    {
      const int lane = tid & 63;
      const int target = base + t + 1;
      for (;;) {
        int v0 = __hip_atomic_load(gslots + lane * 8, __ATOMIC_RELAXED, __HIP_MEMORY_SCOPE_AGENT);
        int v1 = __hip_atomic_load(gslots + (lane + 64) * 8, __ATOMIC_RELAXED, __HIP_MEMORY_SCOPE_AGENT);
        if (!__any((v0 < target) || (v1 < target))) break;
        __builtin_amdgcn_s_sleep(1);
      }
    }
    // no __syncthreads here: spin-exit certifies all step-t hs4 reads retired
    // (hp feeds the acked h store); each thread re-stages only its own slots.

    xr = nxr; xz = nxz; xn = nxn;
    cur ^= 1;
  }
}

// ---------------------------------------------------------------------------
// Launch -- byte-identical flow and ws footprint to proven round 4.
// ---------------------------------------------------------------------------
extern "C" void kernel_launch(void* const* d_in, const int* in_sizes, int n_in,
                              void* d_out, int out_size, void* d_ws, size_t ws_size,
                              hipStream_t stream) {
  const float* x     = (const float*)d_in[0];
  const float* Wih0  = (const float*)d_in[1];
  const float* Whh0  = (const float*)d_in[2];
  const float* bih0  = (const float*)d_in[3];
  const float* bhh0  = (const float*)d_in[4];
  const float* Wih1  = (const float*)d_in[5];
  const float* Whh1  = (const float*)d_in[6];
  const float* bih1  = (const float*)d_in[7];
  const float* bhh1  = (const float*)d_in[8];

  float* out = (float*)d_out;
  float* y1   = out;                       // [T,B,H]
  float* hn0  = out + (size_t)Tlen * BH;   // [B,H]
  float* hn1  = hn0 + BH;                  // [B,H]

  // workspace layout (floats) -- total 67,248,128 floats (PROVEN round-4 size)
  //  [0, 8192)     stamp slots: 8 groups x 32 blocks x 4 waves x 8 ints (32KB)
  //  [8192, +4*BH) h double buffers (slots 0/1 = layer0, 2/3 = layer1)
  //  xg buffer     T*B*3H floats (192 MB)
  //  y0 buffer     T*B*H floats (64 MB)
  float* ws    = (float*)d_ws;
  int*   slots = (int*)d_ws;
  float* hbuf  = ws + 8192;
  float* xgbuf = hbuf + 4 * BH;
  float* y0    = xgbuf + (size_t)Tlen * Bsz * G3;

  const int M = Tlen * Bsz;  // 32768

  hipMemsetAsync(slots, 0, 8192 * sizeof(int), stream);
  hipMemsetAsync(hbuf, 0, BH * sizeof(float), stream);            // layer0 h=0
  hipMemsetAsync(hbuf + 2 * BH, 0, BH * sizeof(float), stream);   // layer1 h=0

  dim3 gemm_grid((M / 128) * (G3 / 128));  // 3072 blocks

  // layer 0 (stamps 1..511)
  gemm_xg<<<gemm_grid, 256, 0, stream>>>(x, Wih0, bih0, xgbuf, M, G3, 256);
  gru_scan<<<256, 256, 0, stream>>>(xgbuf, Whh0, bhh0, y0, hn0, hbuf, slots, 0);

  // layer 1 (stamps 513..1023 -- monotonic past layer 0, no reset needed)
  gemm_xg<<<gemm_grid, 256, 0, stream>>>(y0, Wih1, bih1, xgbuf, M, G3, 512);
  gru_scan<<<256, 256, 0, stream>>>(xgbuf, Whh1, bhh1, y1, hn1, hbuf + 2 * BH, slots, Tlen);
}